// Round 3
// baseline (131.551 us; speedup 1.0000x reference)
//
#include <hip/hip_runtime.h>

#define EPS 1e-6f

__device__ __forceinline__ float elu1(float x) {
    // elu(x) + 1  ==  x > 0 ? x + 1 : exp(x)
    return x > 0.f ? x + 1.f : __expf(x);
}

// ---------------------------------------------------------------------------
// Phase 1: per-WAVE independent 64x64 partial KV over a contiguous s-range.
// No __syncthreads anywhere: each wave owns its own 8 KB LDS slice, so
// prefetched global loads stay in flight under the 1024-FMA compute stretch
// (no barrier-induced vmcnt(0) drain).
// Lane roles: compute tile (m0=( l>>3)*8, d0=(l&7)*8) -> acc[8][8];
// staging slot k: float4 slot l+64k -> row (l>>4)+4k, col (l&15)*4.
// Dump: pkv[chunk][nh][k=i*8+j][l]  (each store instr = 256B contiguous).
// ---------------------------------------------------------------------------
__global__ __launch_bounds__(256) void kv_partial_kernel(
    const float* __restrict__ keys, const float* __restrict__ values,
    const float* __restrict__ mask, float* __restrict__ pkv,
    float* __restrict__ pks, int rowsPerWave)
{
    __shared__ float lds[4][2][16 * 64];   // [wave][K/V][16 s-rows x 64]

    const int nh = blockIdx.x;
    const int n = nh >> 4, h = nh & 15;
    const int t = threadIdx.x;
    const int w = t >> 6, l = t & 63;
    const int chunk = blockIdx.y * 4 + w;
    const int s0 = chunk * rowsPerWave;
    const int tiles = rowsPerWave >> 4;

    float* Ks = lds[w][0];
    float* Vs = lds[w][1];

    const int m0 = (l >> 3) * 8, d0 = (l & 7) * 8;
    const int srow = l >> 4;           // staging row base 0..3
    const int scol = (l & 15) * 4;     // staging col

    const float* kb = keys   + ((size_t)(n * 4096 + s0) * 16 + h) * 64 + scol;
    const float* vb = values + ((size_t)(n * 4096 + s0) * 16 + h) * 64 + scol;
    const float* mb = mask + n * 4096 + s0;

    float4 kr[4], vr[4];
    float mr[4];
    float acc[8][8];
    #pragma unroll
    for (int i = 0; i < 8; ++i)
        #pragma unroll
        for (int j = 0; j < 8; ++j) acc[i][j] = 0.f;
    float4 ks4 = make_float4(0.f, 0.f, 0.f, 0.f);

    // prefetch tile 0 (8 float4 + 4 mask scalars per lane)
    #pragma unroll
    for (int k = 0; k < 4; ++k) {
        const int row = srow + 4 * k;
        kr[k] = *(const float4*)(kb + (size_t)row * 1024);
        vr[k] = *(const float4*)(vb + (size_t)row * 1024);
        mr[k] = mb[row];
    }

    for (int tile = 0; tile < tiles; ++tile) {
        // transform K (elu+mask), accumulate ksum partial, stage both tiles
        #pragma unroll
        for (int k = 0; k < 4; ++k) {
            float4 kk = kr[k];
            const float msk = mr[k];
            kk.x = elu1(kk.x) * msk; kk.y = elu1(kk.y) * msk;
            kk.z = elu1(kk.z) * msk; kk.w = elu1(kk.w) * msk;
            ks4.x += kk.x; ks4.y += kk.y; ks4.z += kk.z; ks4.w += kk.w;
            ((float4*)Ks)[l + 64 * k] = kk;
            ((float4*)Vs)[l + 64 * k] = vr[k];
        }
        // issue next tile's global loads; they fly under the FMA loop below
        if (tile + 1 < tiles) {
            const size_t off = (size_t)(tile + 1) * 16 * 1024;
            #pragma unroll
            for (int k = 0; k < 4; ++k) {
                const int row = srow + 4 * k;
                kr[k] = *(const float4*)(kb + off + (size_t)row * 1024);
                vr[k] = *(const float4*)(vb + off + (size_t)row * 1024);
                mr[k] = mb[(tile + 1) * 16 + row];
            }
        }
        // compute: per s, 4x ds_read_b128 -> 64 FMA (2-way banks, broadcast)
        #pragma unroll
        for (int s = 0; s < 16; ++s) {
            const float4 ka = *(const float4*)&Ks[s * 64 + d0];
            const float4 kc = *(const float4*)&Ks[s * 64 + d0 + 4];
            const float4 va = *(const float4*)&Vs[s * 64 + m0];
            const float4 vc = *(const float4*)&Vs[s * 64 + m0 + 4];
            const float kk[8] = {ka.x, ka.y, ka.z, ka.w, kc.x, kc.y, kc.z, kc.w};
            const float vv[8] = {va.x, va.y, va.z, va.w, vc.x, vc.y, vc.z, vc.w};
            #pragma unroll
            for (int i = 0; i < 8; ++i)
                #pragma unroll
                for (int j = 0; j < 8; ++j)
                    acc[i][j] = fmaf(vv[i], kk[j], acc[i][j]);
        }
    }

    // ksum partial: lane holds cols (l&15)*4..+3; reduce over l>>4 via shuffles
    ks4.x += __shfl_xor(ks4.x, 16, 64); ks4.y += __shfl_xor(ks4.y, 16, 64);
    ks4.z += __shfl_xor(ks4.z, 16, 64); ks4.w += __shfl_xor(ks4.w, 16, 64);
    ks4.x += __shfl_xor(ks4.x, 32, 64); ks4.y += __shfl_xor(ks4.y, 32, 64);
    ks4.z += __shfl_xor(ks4.z, 32, 64); ks4.w += __shfl_xor(ks4.w, 32, 64);
    if (l < 16)
        *(float4*)(pks + ((size_t)chunk * 64 + nh) * 64 + l * 4) = ks4;

    // dump partial: 64 coalesced scalar stores (256B per wave instr)
    float* pb = pkv + ((size_t)chunk * 64 + nh) * 4096;
    #pragma unroll
    for (int i = 0; i < 8; ++i)
        #pragma unroll
        for (int j = 0; j < 8; ++j)
            pb[(i * 8 + j) * 64 + l] = acc[i][j];
}

// ---------------------------------------------------------------------------
// Reduce: kvt[nh][d][m] = sum_c pkv[c][nh][k][l] unscrambled
//         (m = (l>>3)*8 + (k>>3), d = (l&7)*8 + (k&7));
//         ksum[nh][d] = sum_c pks[c][nh][d].
// ---------------------------------------------------------------------------
__global__ __launch_bounds__(256) void kv_reduce_kernel(
    const float* __restrict__ pkv, const float* __restrict__ pks,
    float* __restrict__ kvt, float* __restrict__ ksum, int CH)
{
    const int nh = blockIdx.x;
    const int f4 = blockIdx.y * 256 + threadIdx.x;   // float4 slot 0..1023
    float4 s4 = make_float4(0.f, 0.f, 0.f, 0.f);
    for (int c = 0; c < CH; ++c) {
        const float4 v = *(const float4*)(pkv + ((size_t)c * 64 + nh) * 4096 + f4 * 4);
        s4.x += v.x; s4.y += v.y; s4.z += v.z; s4.w += v.w;
    }
    const float vals[4] = {s4.x, s4.y, s4.z, s4.w};
    const int k = f4 >> 4;            // const over the 4 floats of this slot
    const int lb = (f4 & 15) * 4;
    #pragma unroll
    for (int u = 0; u < 4; ++u) {
        const int l = lb + u;
        const int m = ((l >> 3) << 3) + (k >> 3);
        const int d = ((l & 7) << 3) + (k & 7);
        kvt[(size_t)nh * 4096 + d * 64 + m] = vals[u];
    }
    if (blockIdx.y == 0 && threadIdx.x < 64) {
        float s = 0.f;
        for (int c = 0; c < CH; ++c)
            s += pks[((size_t)c * 64 + nh) * 64 + threadIdx.x];
        ksum[nh * 64 + threadIdx.x] = s;
    }
}

// ---------------------------------------------------------------------------
// Phase 2: out[n,l,h,m] = z_l * sum_d Q'[l,d] * KVT[d,m],
//          z_l = 1/(sum_d Q'[l,d]*Ksum[d] + EPS)
// ---------------------------------------------------------------------------
__global__ __launch_bounds__(256) void out_kernel(
    const float* __restrict__ queries, const float* __restrict__ kvt,
    const float* __restrict__ ksum, float* __restrict__ out)
{
    __shared__ float QsT[64][132];  // [d][l]
    __shared__ float KVs[64][68];   // [d][m]
    __shared__ float Ksm[64];
    __shared__ float Zs[128];

    const int nh = blockIdx.x;
    const int n = nh >> 4, h = nh & 15;
    const int t = threadIdx.x;
    const int l0 = blockIdx.y * 128;

    #pragma unroll
    for (int k = 0; k < 4; ++k) {
        const int idx = t + k * 256;
        const int dd = idx >> 4, seg = idx & 15;
        const float4 v = *(const float4*)(kvt + (size_t)nh * 4096 + idx * 4);
        *(float4*)&KVs[dd][seg * 4] = v;
    }
    if (t < 64) Ksm[t] = ksum[nh * 64 + t];

    #pragma unroll
    for (int k = 0; k < 8; ++k) {
        const int idx = t + k * 256;
        const int row = idx >> 4, seg = idx & 15;
        const size_t g = ((size_t)(n * 4096 + l0 + row) * 16 + h) * 64 + seg * 4;
        float4 q4 = *(const float4*)(queries + g);
        q4.x = elu1(q4.x);
        q4.y = elu1(q4.y);
        q4.z = elu1(q4.z);
        q4.w = elu1(q4.w);
        QsT[seg * 4 + 0][row] = q4.x;
        QsT[seg * 4 + 1][row] = q4.y;
        QsT[seg * 4 + 2][row] = q4.z;
        QsT[seg * 4 + 3][row] = q4.w;
    }
    __syncthreads();

    if (t < 128) {
        float a = 0.f;
        #pragma unroll 8
        for (int d = 0; d < 64; ++d) a = fmaf(QsT[d][t], Ksm[d], a);
        Zs[t] = 1.f / (a + EPS);
    }
    __syncthreads();

    const int mg = t & 7, lg = t >> 3;
    const int m0 = mg * 8, lt = lg * 4;
    float acc[4][8];
    #pragma unroll
    for (int i = 0; i < 4; ++i)
        #pragma unroll
        for (int j = 0; j < 8; ++j) acc[i][j] = 0.f;

    #pragma unroll 4
    for (int d = 0; d < 64; ++d) {
        const float4 q4 = *(const float4*)&QsT[d][lt];
        const float4 a4 = *(const float4*)&KVs[d][m0];
        const float4 b4 = *(const float4*)&KVs[d][m0 + 4];
        const float qq[4] = {q4.x, q4.y, q4.z, q4.w};
        const float mm[8] = {a4.x, a4.y, a4.z, a4.w, b4.x, b4.y, b4.z, b4.w};
        #pragma unroll
        for (int i = 0; i < 4; ++i)
            #pragma unroll
            for (int j = 0; j < 8; ++j)
                acc[i][j] = fmaf(qq[i], mm[j], acc[i][j]);
    }

    #pragma unroll
    for (int i = 0; i < 4; ++i) {
        const float z = Zs[lt + i];
        const size_t g = ((size_t)(n * 4096 + l0 + lt + i) * 16 + h) * 64 + m0;
        float4 o;
        o.x = acc[i][0] * z; o.y = acc[i][1] * z;
        o.z = acc[i][2] * z; o.w = acc[i][3] * z;
        *(float4*)(out + g) = o;
        o.x = acc[i][4] * z; o.y = acc[i][5] * z;
        o.z = acc[i][6] * z; o.w = acc[i][7] * z;
        *(float4*)(out + g + 4) = o;
    }
}

extern "C" void kernel_launch(void* const* d_in, const int* in_sizes, int n_in,
                              void* d_out, int out_size, void* d_ws, size_t ws_size,
                              hipStream_t stream) {
    const float* queries = (const float*)d_in[0];
    const float* keys    = (const float*)d_in[1];
    const float* values  = (const float*)d_in[2];
    const float* mask    = (const float*)d_in[3];
    float* out = (float*)d_out;

    // chunk count: one wave per (nh, chunk); adaptive to workspace size
    int CH = 32;
    while (CH > 4) {
        size_t need = ((size_t)CH * 64 * 4096 + (size_t)CH * 64 * 64 +
                       (size_t)64 * 4096 + 64 * 64) * sizeof(float);
        if (need <= ws_size) break;
        CH >>= 1;
    }
    const int rowsPerWave = 4096 / CH;

    float* pkv  = (float*)d_ws;                         // [CH][64][4096]
    float* pks  = pkv + (size_t)CH * 64 * 4096;         // [CH][64][64]
    float* kvt  = pks + (size_t)CH * 64 * 64;           // [64][64][64] (d,m)
    float* ksum = kvt + (size_t)64 * 4096;              // [64][64]

    kv_partial_kernel<<<dim3(64, CH / 4), 256, 0, stream>>>(keys, values, mask,
                                                            pkv, pks, rowsPerWave);
    kv_reduce_kernel<<<dim3(64, 4), 256, 0, stream>>>(pkv, pks, kvt, ksum, CH);
    out_kernel<<<dim3(64, 32), 256, 0, stream>>>(queries, kvt, ksum, out);
}